// Round 1
// baseline (910.605 us; speedup 1.0000x reference)
//
#include <hip/hip_runtime.h>
#include <math.h>

#define NXg 256
#define NYg 256
#define BIGV 1.0e6f
#define TB 32          // tile is TB x TB cells, 8x8 blocks cover the grid
#define KMAX 96        // cap on local Jacobi iterations (early exit typical)
#define NSWEEP 24      // sequential halo-exchange rounds (>= worst tile-hop path + slack)

// ---------------- init: u = BIG everywhere, seed 4 cells around source ----------------
__global__ void eik_init(const float* __restrict__ f, const float* __restrict__ src,
                         float* __restrict__ u) {
    int t = blockIdx.x * blockDim.x + threadIdx.x;   // 16384 threads, 4 cells each
    float sx = src[0], sy = src[1];
    int ix0 = (int)fminf(fmaxf(floorf(sx), 0.f), (float)(NXg - 2));
    int iy0 = (int)fminf(fmaxf(floorf(sy), 0.f), (float)(NYg - 2));
#pragma unroll
    for (int k = 0; k < 4; ++k) {
        int cid = t + (k << 14);
        int gx = cid >> 8, gy = cid & 255;
        float val = BIGV;
        if ((gx == ix0 || gx == ix0 + 1) && (gy == iy0 || gy == iy0 + 1)) {
            float dx = (float)gx - sx, dy = (float)gy - sy;
            val = sqrtf(dx * dx + dy * dy) * f[cid];   // H == 1
        }
        u[cid] = val;
    }
}

// ---------------- one halo-exchange round: block-local chaotic Jacobi to convergence ----
__global__ __launch_bounds__(256) void eik_sweep(const float* __restrict__ f,
                                                 float* __restrict__ u) {
    __shared__ float us[TB + 2][TB + 2];
    const int t = threadIdx.x;
    const int bx = blockIdx.x & 7, by = blockIdx.x >> 3;
    const int x0 = bx * TB, y0 = by * TB;

    // load tile + 1-cell halo (BIG outside the grid)
    for (int idx = t; idx < (TB + 2) * (TB + 2); idx += 256) {
        int r = idx / (TB + 2), c = idx % (TB + 2);
        int gx = x0 + r - 1, gy = y0 + c - 1;
        float v = BIGV;
        if (gx >= 0 && gx < NXg && gy >= 0 && gy < NYg) v = u[(gx << 8) + gy];
        us[r][c] = v;
    }

    // per-thread cells: cid = t + 256k -> (r, c) inside the tile
    float fhr[4], tfh2[4];
#pragma unroll
    for (int k = 0; k < 4; ++k) {
        int cid = t + (k << 8);
        int r = cid >> 5, c = cid & 31;
        float fv = f[((x0 + r) << 8) + (y0 + c)];      // fh = f * H, H == 1
        fhr[k] = fv;
        tfh2[k] = 2.0f * fv * fv;
    }
    __syncthreads();

    for (int it = 0; it < KMAX; ++it) {
        int ch = 0;
#pragma unroll
        for (int k = 0; k < 4; ++k) {
            int cid = t + (k << 8);
            int r = cid >> 5, c = cid & 31;
            float a  = fminf(us[r][c + 1], us[r + 2][c + 1]);   // upwind min along x
            float b  = fminf(us[r + 1][c], us[r + 1][c + 2]);   // upwind min along y
            float u0 = us[r + 1][c + 1];
            float one  = fminf(a, b) + fhr[k];
            float diff = a - b;
            float disc = fmaxf(tfh2[k] - diff * diff, 0.f);
            float two  = 0.5f * (a + b + sqrtf(disc));
            float cand = (fabsf(diff) >= fhr[k]) ? one : two;
            if (cand < u0) { us[r + 1][c + 1] = cand; ch = 1; } // monotone in-place (chaotic-safe)
        }
        if (__syncthreads_count(ch) == 0) break;   // locally converged w.r.t. frozen halos
    }

    // write back interior (each cell owned by exactly one block)
#pragma unroll
    for (int k = 0; k < 4; ++k) {
        int cid = t + (k << 8);
        int r = cid >> 5, c = cid & 31;
        u[((x0 + r) << 8) + (y0 + c)] = us[r + 1][c + 1];
    }
}

// ---------------- bilinear interp at picks + add origin time ----------------
__global__ void eik_interp(const float* __restrict__ u,
                           const float* __restrict__ ex,
                           const float* __restrict__ ey,
                           const float* __restrict__ et,
                           float* __restrict__ out, int n) {
    int i = blockIdx.x * blockDim.x + threadIdx.x;
    int stride = gridDim.x * blockDim.x;
    for (; i < n; i += stride) {
        float x = ex[i], y = ey[i];
        int ix0 = (int)fminf(fmaxf(floorf(x), 0.f), (float)(NXg - 2));
        int iy0 = (int)fminf(fmaxf(floorf(y), 0.f), (float)(NYg - 2));
        float xc = fminf(fmaxf(x, 0.f), (float)(NXg - 1));
        float yc = fminf(fmaxf(y, 0.f), (float)(NYg - 1));
        float fx0 = (float)ix0, fy0 = (float)iy0;
        float wx0 = xc - fx0, wx1 = (fx0 + 1.f) - xc;
        float wy0 = yc - fy0, wy1 = (fy0 + 1.f) - yc;
        int base = (ix0 << 8) + iy0;
        float Q00 = u[base],       Q01 = u[base + 1];
        float Q10 = u[base + 256], Q11 = u[base + 257];
        float tt = Q00 * wx1 * wy1 + Q10 * wx0 * wy1
                 + Q01 * wx1 * wy0 + Q11 * wx0 * wy0;
        out[i] = et[i] + tt;
    }
}

extern "C" void kernel_launch(void* const* d_in, const int* in_sizes, int n_in,
                              void* d_out, int out_size, void* d_ws, size_t ws_size,
                              hipStream_t stream) {
    const float* f   = (const float*)d_in[0];
    const float* src = (const float*)d_in[1];
    const float* ex  = (const float*)d_in[2];
    const float* ey  = (const float*)d_in[3];
    const float* et  = (const float*)d_in[4];
    float* out = (float*)d_out;
    float* u   = (float*)d_ws;               // 256 KB travel-time table
    int n = in_sizes[2];

    eik_init<<<64, 256, 0, stream>>>(f, src, u);
    for (int r = 0; r < NSWEEP; ++r)
        eik_sweep<<<64, 256, 0, stream>>>(f, u);
    eik_interp<<<2048, 256, 0, stream>>>(u, ex, ey, et, out, n);
}